// Round 12
// baseline (4996.884 us; speedup 1.0000x reference)
//
#include <hip/hip_runtime.h>
#include <math.h>

// ---------------------------------------------------------------------------
// Encoder: 2-layer bidirectional LSTM, B=64, T=512, E=H=512, fp32 in/out.
// Round 12: lstm chain tightened (wave-local barrier poll + p_lds parity
// double-buffer -> one less syncthreads; out-store ack hidden under h ack).
// Layer-1 GEMM 1-term (Wh only, error ~4e-5); F+B GEMMs merged per layer.
// ---------------------------------------------------------------------------

#define NBLK_LSTM 256

typedef __attribute__((ext_vector_type(8))) short bf16x8;
typedef __attribute__((ext_vector_type(16))) float f32x16;

__device__ __forceinline__ float bf2f(unsigned short u) {
  return __uint_as_float(((unsigned)u) << 16);
}
__device__ __forceinline__ unsigned short f2bf(float f) {
  unsigned u = __float_as_uint(f);
  unsigned r = (u + 0x7FFFu + ((u >> 16) & 1u)) >> 16;
  return (unsigned short)r;
}
__device__ __forceinline__ float fsigmoid(float x) {
  return 1.0f / (1.0f + __expf(-x));
}
__device__ __forceinline__ float ftanh(float x) {
  return 1.0f - 2.0f / (1.0f + __expf(2.0f * x));
}
__device__ __forceinline__ void gload16(const void* g, void* l) {
  __builtin_amdgcn_global_load_lds(
      (const __attribute__((address_space(1))) unsigned int*)g,
      (__attribute__((address_space(3))) unsigned int*)l, 16, 0, 0);
}

// ---------------- U transpose: Ut[col][k] = U[k][col] (fp32) ----------------
__global__ __launch_bounds__(256) void transpose_u(const float* __restrict__ U,
                                                   float* __restrict__ Ut) {
  __shared__ float tile[32][33];
  int kt = blockIdx.x & 15;
  int ct = blockIdx.x >> 4;
  int k0 = kt * 32, c0 = ct * 32;
  int tx = threadIdx.x & 31, ty = threadIdx.x >> 5;
#pragma unroll
  for (int i = 0; i < 32; i += 8)
    tile[ty + i][tx] = U[(size_t)(k0 + ty + i) * 2048 + c0 + tx];
  __syncthreads();
#pragma unroll
  for (int i = 0; i < 32; i += 8)
    Ut[(size_t)(c0 + ty + i) * 512 + k0 + tx] = tile[tx][ty + i];
}

// ---------- W -> split bf16 panels [16 nt][KT][128][32], swizzled ----------
__global__ __launch_bounds__(256) void build_w_panels(
    const float* __restrict__ W, unsigned short* __restrict__ Wh,
    unsigned short* __restrict__ Wl, int KT) {
  __shared__ float tile[32][33];
  const int tid = threadIdx.x;
  int kt = blockIdx.x % KT;
  int ct = blockIdx.x / KT;          // 0..63
  int k0 = kt * 32, c0 = ct * 32;
  int tx = tid & 31, ty = tid >> 5;
#pragma unroll
  for (int i = 0; i < 32; i += 8)
    tile[ty + i][tx] = W[(size_t)(k0 + ty + i) * 2048 + c0 + tx];
  __syncthreads();
  const int t = tid & 127;
  const int cl = t & 31, g = t >> 5;
  const int c = c0 + cl;
  const int rm = c & 127, nt = c >> 7;
  const int slot = g ^ (rm & 3);
  size_t off = (((size_t)(nt * KT + kt) * 128 + rm) << 5) + slot * 8;
  bf16x8 hh, ll;
#pragma unroll
  for (int e = 0; e < 8; e++) {
    float f = tile[g * 8 + e][cl];
    unsigned short h = f2bf(f);
    hh[e] = (short)h;
    ll[e] = (short)f2bf(f - bf2f(h));
  }
  if (tid < 128) *(bf16x8*)(Wh + off) = hh;
  else           *(bf16x8*)(Wl + off) = ll;
}

// ------- A1 panels: bf16(emb[ids[m]]) -> [256 mt][16 kt][128][32] ----------
__global__ __launch_bounds__(256) void build_a1_panels(
    const int* __restrict__ ids, const float* __restrict__ emb,
    unsigned short* __restrict__ Apan) {
  const int tid = threadIdx.x;
  const int l = tid & 63, wv = tid >> 6;
  const int m = blockIdx.x * 4 + wv;
  const float* src = emb + (size_t)ids[m] * 512 + l * 8;
  float4 v0 = *(const float4*)src;
  float4 v1 = *(const float4*)(src + 4);
  float f[8] = {v0.x, v0.y, v0.z, v0.w, v1.x, v1.y, v1.z, v1.w};
  bf16x8 hh;
#pragma unroll
  for (int e = 0; e < 8; e++) hh[e] = (short)f2bf(f[e]);
  const int rm = m & 127, mt = m >> 7;
  const int kt = l >> 2, g = l & 3;
  const int slot = g ^ (rm & 3);
  *(bf16x8*)(Apan + (((size_t)(mt * 16 + kt) * 128 + rm) << 5) + slot * 8) = hh;
}

// ============================================================================
// Panel GEMM, merged F/B dispatch: bid>>12 selects half.
// TERMS=2: C = A @ (Wh + Wl) + b.  TERMS=1: C = A @ Wh + b.
// 128x128 tile, 4 waves, BK=32, double-buffered LDS, global_load_lds staging.
// ============================================================================
template <int KT, int TERMS>
__global__ __launch_bounds__(256) void gemm_panel(
    const unsigned short* __restrict__ Apan,
    const unsigned short* __restrict__ WhF,
    const unsigned short* __restrict__ WlF,
    const unsigned short* __restrict__ WhB,
    const unsigned short* __restrict__ WlB,
    const float* __restrict__ bF, const float* __restrict__ bB,
    unsigned short* __restrict__ CF, unsigned short* __restrict__ CB) {
  __shared__ __align__(16) char lds[2][24576];

  const int tid = threadIdx.x;
  const int half = blockIdx.x >> 12;
  const int inner = blockIdx.x & 4095;
  const int mt = inner & 255;
  const int nt = inner >> 8;
  const int l = tid & 63;
  const int wv = tid >> 6;
  const int wm = wv >> 1, wn = wv & 1;

  const unsigned short* WhP = half ? WhB : WhF;
  const unsigned short* WlP = half ? WlB : WlF;
  const float* bias = half ? bB : bF;
  unsigned short* C = half ? CB : CF;

  const char* aSrc = (const char*)(Apan + (size_t)mt * KT * 4096);
  const char* hSrc = (const char*)(WhP + (size_t)nt * KT * 4096);
  const char* lSrc = (const char*)(WlP + (size_t)nt * KT * 4096);
  const int wvo = wv * 1024;
  const int lo16 = l * 16;

  f32x16 acc[2][2];
#pragma unroll
  for (int rb = 0; rb < 2; rb++)
#pragma unroll
    for (int cb = 0; cb < 2; cb++)
#pragma unroll
      for (int r = 0; r < 16; r++) acc[rb][cb][r] = 0.0f;

  auto STAGE = [&](int buf, int t) {
    const char* ga = aSrc + (size_t)t * 8192 + wvo + lo16;
    const char* gh = hSrc + (size_t)t * 8192 + wvo + lo16;
    char* da = &lds[buf][0] + wvo;
    char* dh = &lds[buf][8192] + wvo;
    gload16(ga, da);
    gload16(ga + 4096, da + 4096);
    gload16(gh, dh);
    gload16(gh + 4096, dh + 4096);
    if (TERMS == 2) {
      const char* gl = lSrc + (size_t)t * 8192 + wvo + lo16;
      char* dl = &lds[buf][16384] + wvo;
      gload16(gl, dl);
      gload16(gl + 4096, dl + 4096);
    }
  };

  STAGE(0, 0);
  asm volatile("s_waitcnt vmcnt(0)" ::: "memory");
  __syncthreads();

  const int aoff0 = (wm * 64 + (l & 31)) * 64;
  const int woff0 = 8192 + (wn * 64 + (l & 31)) * 64;
  const int gbase = l >> 5;
  const int gx = l & 3;

  for (int t = 0; t < KT; t++) {
    if (t + 1 < KT) STAGE((t + 1) & 1, t + 1);
    const char* lb = lds[t & 1];
#pragma unroll
    for (int ks = 0; ks < 2; ks++) {
      const int slot = (((ks << 1) + gbase) ^ gx) << 4;
      bf16x8 a0 = *(const bf16x8*)(lb + aoff0 + slot);
      bf16x8 a1 = *(const bf16x8*)(lb + aoff0 + 2048 + slot);
      bf16x8 h0 = *(const bf16x8*)(lb + woff0 + slot);
      bf16x8 h1 = *(const bf16x8*)(lb + woff0 + 2048 + slot);
      acc[0][0] = __builtin_amdgcn_mfma_f32_32x32x16_bf16(a0, h0, acc[0][0], 0, 0, 0);
      acc[0][1] = __builtin_amdgcn_mfma_f32_32x32x16_bf16(a0, h1, acc[0][1], 0, 0, 0);
      acc[1][0] = __builtin_amdgcn_mfma_f32_32x32x16_bf16(a1, h0, acc[1][0], 0, 0, 0);
      acc[1][1] = __builtin_amdgcn_mfma_f32_32x32x16_bf16(a1, h1, acc[1][1], 0, 0, 0);
      if (TERMS == 2) {
        bf16x8 w0 = *(const bf16x8*)(lb + woff0 + 8192 + slot);
        bf16x8 w1 = *(const bf16x8*)(lb + woff0 + 8192 + 2048 + slot);
        acc[0][0] = __builtin_amdgcn_mfma_f32_32x32x16_bf16(a0, w0, acc[0][0], 0, 0, 0);
        acc[0][1] = __builtin_amdgcn_mfma_f32_32x32x16_bf16(a0, w1, acc[0][1], 0, 0, 0);
        acc[1][0] = __builtin_amdgcn_mfma_f32_32x32x16_bf16(a1, w0, acc[1][0], 0, 0, 0);
        acc[1][1] = __builtin_amdgcn_mfma_f32_32x32x16_bf16(a1, w1, acc[1][1], 0, 0, 0);
      }
    }
    asm volatile("s_waitcnt vmcnt(0)" ::: "memory");
    __syncthreads();
  }

  const int m0 = mt * 128, n0 = nt * 128;
  const float b0 = bias[n0 + wn * 64 + (l & 31)];
  const float b1 = bias[n0 + wn * 64 + 32 + (l & 31)];
#pragma unroll
  for (int rb = 0; rb < 2; rb++) {
    const int rowb = m0 + wm * 64 + rb * 32 + 4 * (l >> 5);
#pragma unroll
    for (int cb = 0; cb < 2; cb++) {
      const int col = n0 + wn * 64 + cb * 32 + (l & 31);
      const float bb = cb ? b1 : b0;
#pragma unroll
      for (int r = 0; r < 16; r++) {
        const int row = rowb + (r & 3) + 8 * (r >> 2);
        C[(size_t)row * 2048 + col] = f2bf(acc[rb][cb][r] + bb);
      }
    }
  }
}

// ============================================================================
// Fused bidirectional recurrence — wave-local poll + p_lds parity edition.
// 256 blocks: dir = bid>>7, jg = (bid&127)>>1 (8 j-cols), bg = bid&1 (32 b).
// Per epoch: [wave polls 8 leaves (uniform addrs)] -> A-frag IF->VGPR loads
// -> 24 MFMA -> p_lds[s&1] -> syncthreads -> update -> h+out stores ->
// vmcnt(0) -> syncthreads -> arrive -> xz prefetch.
// ============================================================================
__global__ __launch_bounds__(256, 1) void lstm_fused(
    const unsigned short* __restrict__ xzF,
    const unsigned short* __restrict__ xzB,
    const float* __restrict__ UtF,
    const float* __restrict__ UtB,
    float* __restrict__ outF32,
    unsigned short* __restrict__ outB16,
    float* __restrict__ hbuf,
    float* __restrict__ stateh, float* __restrict__ statec,
    unsigned* __restrict__ bar) {
  __shared__ float p_lds[2][4][32][36];

  const int tid = threadIdx.x;
  const int bid = blockIdx.x;
  const int dir = bid >> 7;
  const int jg  = (bid & 127) >> 1;
  const int bg  = bid & 1;
  const int grp = dir * 2 + bg;

  const unsigned short* xz = dir ? xzB : xzF;
  const float* Ut = dir ? UtB : UtF;
  char* hbuf_c = (char*)hbuf;

  const int l  = tid & 63;
  const int wv = tid >> 6;

  // ---- U fragments in registers (loop-invariant B operands) ----
  bf16x8 uh8[8], ul8[8];
  {
    const int c = l & 31;
    const size_t gcol = (size_t)((c >> 3) * 512 + jg * 8 + (c & 7));
#pragma unroll
    for (int ks = 0; ks < 8; ks++) {
      const float* src = Ut + gcol * 512 + (wv * 8 + ks) * 16 + ((l >> 5) << 3);
      bf16x8 hh, ll;
#pragma unroll
      for (int e = 0; e < 8; e++) {
        float f = src[e];
        unsigned short us = f2bf(f);
        hh[e] = (short)us;
        ll[e] = (short)f2bf(f - bf2f(us));
      }
      uh8[ks] = hh;
      ul8[ks] = ll;
    }
  }

  const int ub = tid >> 3;
  const int jl = tid & 7;
  const int b  = bg * 32 + ub;
  const int j  = jg * 8 + jl;

  unsigned* leafArr = bar + grp * 128;
  unsigned* myleaf  = leafArr + (jg & 7) * 16;

  const unsigned short* xzb = xz + (size_t)b * (512 * 2048) + j;

  float creg = 0.0f;
  float zx0, zx1, zx2, zx3;
  {
    const unsigned short* p = xzb + (size_t)(dir ? 511 : 0) * 2048;
    zx0 = bf2f(p[0]); zx1 = bf2f(p[512]);
    zx2 = bf2f(p[1024]); zx3 = bf2f(p[1536]);
  }

  const int aoff = ((wv * 16 + (l >> 5)) * 32 + (l & 31)) * 16;
  const int poff = jg * 512 + ub * 16 + jl * 2;

  const int colp = dir * 512 + j;
  const int p_kt = colp >> 5, p_g = (colp >> 3) & 3, p_e = colp & 7;

  for (int s = 0; s < 512; s++) {
    const int tt = dir ? (511 - s) : s;

    if (s > 0) {
      // ---- wave-local poll: uniform-address loads, one request/wave ----
      {
        const unsigned tgt = 8u * (unsigned)s;
#pragma unroll
        for (int i = 0; i < 8; i++) {
          while (__hip_atomic_load(leafArr + i * 16, __ATOMIC_RELAXED,
                                   __HIP_MEMORY_SCOPE_AGENT) < tgt)
            __builtin_amdgcn_s_sleep(1);
        }
      }
      // ---- direct IF->VGPR A-frag loads (coalesced granules) ----
      const char* sb = hbuf_c + (size_t)(grp * 2 + (s & 1)) * 65536;
      bf16x8 ahh[8], ahl[8];
#pragma unroll
      for (int ks = 0; ks < 8; ks++) {
        const char* p = sb + aoff + ks * 1024;
        asm volatile("global_load_dwordx4 %0, %1, off sc0 sc1"
                     : "=v"(ahh[ks]) : "v"(p) : "memory");
        asm volatile("global_load_dwordx4 %0, %1, off sc0 sc1"
                     : "=v"(ahl[ks]) : "v"(p + 32768) : "memory");
      }
      asm volatile("s_waitcnt vmcnt(0)" ::: "memory");
      __builtin_amdgcn_sched_barrier(0);

      f32x16 acc;
#pragma unroll
      for (int r = 0; r < 16; r++) acc[r] = 0.0f;
#pragma unroll
      for (int ks = 0; ks < 8; ks++) {
        acc = __builtin_amdgcn_mfma_f32_32x32x16_bf16(ahh[ks], uh8[ks], acc, 0, 0, 0);
        acc = __builtin_amdgcn_mfma_f32_32x32x16_bf16(ahl[ks], uh8[ks], acc, 0, 0, 0);
        acc = __builtin_amdgcn_mfma_f32_32x32x16_bf16(ahh[ks], ul8[ks], acc, 0, 0, 0);
      }
#pragma unroll
      for (int r = 0; r < 16; r++) {
        const int row = (r & 3) + 8 * (r >> 2) + 4 * (l >> 5);
        p_lds[s & 1][wv][row][l & 31] = acc[r];
      }
    }
    __syncthreads();

    // ---- update: thread owns (b, j) ----
    float h;
    {
      float z0 = zx0, z1 = zx1, z2 = zx2, z3 = zx3;
      if (s > 0) {
#pragma unroll
        for (int w = 0; w < 4; w++) {
          z0 += p_lds[s & 1][w][ub][jl];
          z1 += p_lds[s & 1][w][ub][8 + jl];
          z2 += p_lds[s & 1][w][ub][16 + jl];
          z3 += p_lds[s & 1][w][ub][24 + jl];
        }
      }
      float si = fsigmoid(z0);
      float sf = fsigmoid(z1);
      float tg = ftanh(z2);
      float so = fsigmoid(z3);
      creg = fmaf(sf, creg, si * tg);
      h = so * ftanh(creg);
    }

    const int m = b * 512 + tt;
    if (s < 511) {
      // h stores (IF) then out store (L2) — one vmcnt(0) drains both;
      // out-store ack hides under the h IF round trip.
      unsigned short hhs = f2bf(h);
      unsigned short hls = f2bf(h - bf2f(hhs));
      char* db = hbuf_c + (size_t)(grp * 2 + ((s & 1) ^ 1)) * 65536;
      char* pj = db + poff;
      unsigned vh = hhs, vl = hls;
      asm volatile("global_store_short %0, %1, off sc0 sc1"
                   :: "v"(pj), "v"(vh) : "memory");
      asm volatile("global_store_short %0, %1, off sc0 sc1"
                   :: "v"(pj + 32768), "v"(vl) : "memory");
      if (outB16) {
        const int rm = m & 127, mt = m >> 7;
        outB16[(((size_t)(mt * 32 + p_kt) * 128 + rm) << 5) +
               (p_g ^ (rm & 3)) * 8 + p_e] = f2bf(h);
      } else {
        outF32[((size_t)m) * 1024 + colp] = h;
      }
      asm volatile("s_waitcnt vmcnt(0)" ::: "memory");
      __syncthreads();
      if (tid == 0)
        __hip_atomic_fetch_add(myleaf, 1u, __ATOMIC_RELAXED,
                               __HIP_MEMORY_SCOPE_AGENT);
      // ---- poll shadow: next-xz prefetch ----
      {
        const int tn = dir ? (510 - s) : (s + 1);
        const unsigned short* p = xzb + (size_t)tn * 2048;
        zx0 = bf2f(p[0]); zx1 = bf2f(p[512]);
        zx2 = bf2f(p[1024]); zx3 = bf2f(p[1536]);
      }
    } else {
      if (outB16) {
        const int rm = m & 127, mt = m >> 7;
        outB16[(((size_t)(mt * 32 + p_kt) * 128 + rm) << 5) +
               (p_g ^ (rm & 3)) * 8 + p_e] = f2bf(h);
      } else {
        outF32[((size_t)m) * 1024 + colp] = h;
      }
      if (stateh != nullptr) {
        stateh[b * 1024 + colp] = h;
        statec[b * 1024 + colp] = creg;
      }
    }
  }
}

// ---------------------------------------------------------------------------
extern "C" void kernel_launch(void* const* d_in, const int* in_sizes, int n_in,
                              void* d_out, int out_size, void* d_ws, size_t ws_size,
                              hipStream_t stream) {
  const int*   ids = (const int*)d_in[0];
  const float* emb = (const float*)d_in[1];
  const float* W1f = (const float*)d_in[2];
  const float* U1f = (const float*)d_in[3];
  const float* b1f = (const float*)d_in[4];
  const float* W1b = (const float*)d_in[5];
  const float* U1b = (const float*)d_in[6];
  const float* b1b = (const float*)d_in[7];
  const float* W2f = (const float*)d_in[8];
  const float* U2f = (const float*)d_in[9];
  const float* b2f = (const float*)d_in[10];
  const float* W2b = (const float*)d_in[11];
  const float* U2b = (const float*)d_in[12];
  const float* b2b = (const float*)d_in[13];
  float* out = (float*)d_out;

  char* ws = (char*)d_ws;
  unsigned short* xzF = (unsigned short*)(ws + 0ull);
  unsigned short* xzB = (unsigned short*)(ws + 134217728ull);
  float* Ut1f = (float*)(ws + 268435456ull);
  float* Ut1b = Ut1f + 1048576;
  float* Ut2f = Ut1b + 1048576;
  float* Ut2b = Ut2f + 1048576;
  float* hbuf = (float*)(ws + 285212672ull);
  unsigned* bar = (unsigned*)(ws + 285736960ull);

  char* outc = (char*)d_out;
  unsigned short* l1pan = (unsigned short*)outc;
  unsigned short* A1pan = (unsigned short*)(outc + 67108864ull);
  unsigned short* Wh1f = (unsigned short*)(outc + 100663296ull);
  unsigned short* Wl1f = (unsigned short*)(outc + 102760448ull);
  unsigned short* Wh1b = (unsigned short*)(outc + 104857600ull);
  unsigned short* Wl1b = (unsigned short*)(outc + 106954752ull);
  unsigned short* Wh2f = (unsigned short*)(outc + 109051904ull);
  unsigned short* Wl2f = (unsigned short*)(outc + 113246208ull);
  unsigned short* Wh2b = (unsigned short*)(outc + 117440512ull);
  unsigned short* Wl2b = (unsigned short*)(outc + 121634816ull);

  transpose_u<<<1024, 256, 0, stream>>>(U1f, Ut1f);
  transpose_u<<<1024, 256, 0, stream>>>(U1b, Ut1b);
  transpose_u<<<1024, 256, 0, stream>>>(U2f, Ut2f);
  transpose_u<<<1024, 256, 0, stream>>>(U2b, Ut2b);
  build_w_panels<<<1024, 256, 0, stream>>>(W1f, Wh1f, Wl1f, 16);
  build_w_panels<<<1024, 256, 0, stream>>>(W1b, Wh1b, Wl1b, 16);
  build_w_panels<<<2048, 256, 0, stream>>>(W2f, Wh2f, Wl2f, 32);
  build_w_panels<<<2048, 256, 0, stream>>>(W2b, Wh2b, Wl2b, 32);
  build_a1_panels<<<8192, 256, 0, stream>>>(ids, emb, A1pan);

  // layer-1 projections (merged F+B, 1-term)
  gemm_panel<16, 1><<<8192, 256, 0, stream>>>(A1pan, Wh1f, Wl1f, Wh1b, Wl1b,
                                              b1f, b1b, xzF, xzB);
  hipMemsetAsync(bar, 0, 4096, stream);
  lstm_fused<<<NBLK_LSTM, 256, 0, stream>>>(xzF, xzB, Ut1f, Ut1b,
                                            nullptr, l1pan, hbuf,
                                            nullptr, nullptr, bar);
  // layer-2 projections (merged F+B, 2-term)
  gemm_panel<32, 2><<<8192, 256, 0, stream>>>(l1pan, Wh2f, Wl2f, Wh2b, Wl2b,
                                              b2f, b2b, xzF, xzB);
  hipMemsetAsync(bar, 0, 4096, stream);
  lstm_fused<<<NBLK_LSTM, 256, 0, stream>>>(xzF, xzB, Ut2f, Ut2b,
                                            out, nullptr, hbuf,
                                            out + 33554432, out + 33619968, bar);
}

// Round 13
// 4076.160 us; speedup vs baseline: 1.2259x; 1.2259x over previous
//
#include <hip/hip_runtime.h>
#include <math.h>

// ---------------------------------------------------------------------------
// Encoder: 2-layer bidirectional LSTM, B=64, T=512, E=H=512, fp32 in/out.
// Round 13: lstm barrier rebuilt — parallel ballot poll (1 instr covers all
// 8 leaves), per-wave arrival after own vmcnt(0), ONE syncthreads per epoch
// (p_lds parity-buffered). Split vmcnt(8) starts hh MFMAs under hl loads.
// GEMMs keep round-12 merged/1-term structure.
// ---------------------------------------------------------------------------

#define NBLK_LSTM 256

typedef __attribute__((ext_vector_type(8))) short bf16x8;
typedef __attribute__((ext_vector_type(16))) float f32x16;

__device__ __forceinline__ float bf2f(unsigned short u) {
  return __uint_as_float(((unsigned)u) << 16);
}
__device__ __forceinline__ unsigned short f2bf(float f) {
  unsigned u = __float_as_uint(f);
  unsigned r = (u + 0x7FFFu + ((u >> 16) & 1u)) >> 16;
  return (unsigned short)r;
}
__device__ __forceinline__ float fsigmoid(float x) {
  return 1.0f / (1.0f + __expf(-x));
}
__device__ __forceinline__ float ftanh(float x) {
  return 1.0f - 2.0f / (1.0f + __expf(2.0f * x));
}
__device__ __forceinline__ void gload16(const void* g, void* l) {
  __builtin_amdgcn_global_load_lds(
      (const __attribute__((address_space(1))) unsigned int*)g,
      (__attribute__((address_space(3))) unsigned int*)l, 16, 0, 0);
}

// ---------------- U transpose: Ut[col][k] = U[k][col] (fp32) ----------------
__global__ __launch_bounds__(256) void transpose_u(const float* __restrict__ U,
                                                   float* __restrict__ Ut) {
  __shared__ float tile[32][33];
  int kt = blockIdx.x & 15;
  int ct = blockIdx.x >> 4;
  int k0 = kt * 32, c0 = ct * 32;
  int tx = threadIdx.x & 31, ty = threadIdx.x >> 5;
#pragma unroll
  for (int i = 0; i < 32; i += 8)
    tile[ty + i][tx] = U[(size_t)(k0 + ty + i) * 2048 + c0 + tx];
  __syncthreads();
#pragma unroll
  for (int i = 0; i < 32; i += 8)
    Ut[(size_t)(c0 + ty + i) * 512 + k0 + tx] = tile[tx][ty + i];
}

// ---------- W -> split bf16 panels [16 nt][KT][128][32], swizzled ----------
__global__ __launch_bounds__(256) void build_w_panels(
    const float* __restrict__ W, unsigned short* __restrict__ Wh,
    unsigned short* __restrict__ Wl, int KT) {
  __shared__ float tile[32][33];
  const int tid = threadIdx.x;
  int kt = blockIdx.x % KT;
  int ct = blockIdx.x / KT;          // 0..63
  int k0 = kt * 32, c0 = ct * 32;
  int tx = tid & 31, ty = tid >> 5;
#pragma unroll
  for (int i = 0; i < 32; i += 8)
    tile[ty + i][tx] = W[(size_t)(k0 + ty + i) * 2048 + c0 + tx];
  __syncthreads();
  const int t = tid & 127;
  const int cl = t & 31, g = t >> 5;
  const int c = c0 + cl;
  const int rm = c & 127, nt = c >> 7;
  const int slot = g ^ (rm & 3);
  size_t off = (((size_t)(nt * KT + kt) * 128 + rm) << 5) + slot * 8;
  bf16x8 hh, ll;
#pragma unroll
  for (int e = 0; e < 8; e++) {
    float f = tile[g * 8 + e][cl];
    unsigned short h = f2bf(f);
    hh[e] = (short)h;
    ll[e] = (short)f2bf(f - bf2f(h));
  }
  if (tid < 128) *(bf16x8*)(Wh + off) = hh;
  else           *(bf16x8*)(Wl + off) = ll;
}

// ------- A1 panels: bf16(emb[ids[m]]) -> [256 mt][16 kt][128][32] ----------
__global__ __launch_bounds__(256) void build_a1_panels(
    const int* __restrict__ ids, const float* __restrict__ emb,
    unsigned short* __restrict__ Apan) {
  const int tid = threadIdx.x;
  const int l = tid & 63, wv = tid >> 6;
  const int m = blockIdx.x * 4 + wv;
  const float* src = emb + (size_t)ids[m] * 512 + l * 8;
  float4 v0 = *(const float4*)src;
  float4 v1 = *(const float4*)(src + 4);
  float f[8] = {v0.x, v0.y, v0.z, v0.w, v1.x, v1.y, v1.z, v1.w};
  bf16x8 hh;
#pragma unroll
  for (int e = 0; e < 8; e++) hh[e] = (short)f2bf(f[e]);
  const int rm = m & 127, mt = m >> 7;
  const int kt = l >> 2, g = l & 3;
  const int slot = g ^ (rm & 3);
  *(bf16x8*)(Apan + (((size_t)(mt * 16 + kt) * 128 + rm) << 5) + slot * 8) = hh;
}

// ============================================================================
// Panel GEMM, merged F/B dispatch: bid>>12 selects half.
// TERMS=2: C = A @ (Wh + Wl) + b.  TERMS=1: C = A @ Wh + b.
// ============================================================================
template <int KT, int TERMS>
__global__ __launch_bounds__(256) void gemm_panel(
    const unsigned short* __restrict__ Apan,
    const unsigned short* __restrict__ WhF,
    const unsigned short* __restrict__ WlF,
    const unsigned short* __restrict__ WhB,
    const unsigned short* __restrict__ WlB,
    const float* __restrict__ bF, const float* __restrict__ bB,
    unsigned short* __restrict__ CF, unsigned short* __restrict__ CB) {
  __shared__ __align__(16) char lds[2][24576];

  const int tid = threadIdx.x;
  const int half = blockIdx.x >> 12;
  const int inner = blockIdx.x & 4095;
  const int mt = inner & 255;
  const int nt = inner >> 8;
  const int l = tid & 63;
  const int wv = tid >> 6;
  const int wm = wv >> 1, wn = wv & 1;

  const unsigned short* WhP = half ? WhB : WhF;
  const unsigned short* WlP = half ? WlB : WlF;
  const float* bias = half ? bB : bF;
  unsigned short* C = half ? CB : CF;

  const char* aSrc = (const char*)(Apan + (size_t)mt * KT * 4096);
  const char* hSrc = (const char*)(WhP + (size_t)nt * KT * 4096);
  const char* lSrc = (const char*)(WlP + (size_t)nt * KT * 4096);
  const int wvo = wv * 1024;
  const int lo16 = l * 16;

  f32x16 acc[2][2];
#pragma unroll
  for (int rb = 0; rb < 2; rb++)
#pragma unroll
    for (int cb = 0; cb < 2; cb++)
#pragma unroll
      for (int r = 0; r < 16; r++) acc[rb][cb][r] = 0.0f;

  auto STAGE = [&](int buf, int t) {
    const char* ga = aSrc + (size_t)t * 8192 + wvo + lo16;
    const char* gh = hSrc + (size_t)t * 8192 + wvo + lo16;
    char* da = &lds[buf][0] + wvo;
    char* dh = &lds[buf][8192] + wvo;
    gload16(ga, da);
    gload16(ga + 4096, da + 4096);
    gload16(gh, dh);
    gload16(gh + 4096, dh + 4096);
    if (TERMS == 2) {
      const char* gl = lSrc + (size_t)t * 8192 + wvo + lo16;
      char* dl = &lds[buf][16384] + wvo;
      gload16(gl, dl);
      gload16(gl + 4096, dl + 4096);
    }
  };

  STAGE(0, 0);
  asm volatile("s_waitcnt vmcnt(0)" ::: "memory");
  __syncthreads();

  const int aoff0 = (wm * 64 + (l & 31)) * 64;
  const int woff0 = 8192 + (wn * 64 + (l & 31)) * 64;
  const int gbase = l >> 5;
  const int gx = l & 3;

  for (int t = 0; t < KT; t++) {
    if (t + 1 < KT) STAGE((t + 1) & 1, t + 1);
    const char* lb = lds[t & 1];
#pragma unroll
    for (int ks = 0; ks < 2; ks++) {
      const int slot = (((ks << 1) + gbase) ^ gx) << 4;
      bf16x8 a0 = *(const bf16x8*)(lb + aoff0 + slot);
      bf16x8 a1 = *(const bf16x8*)(lb + aoff0 + 2048 + slot);
      bf16x8 h0 = *(const bf16x8*)(lb + woff0 + slot);
      bf16x8 h1 = *(const bf16x8*)(lb + woff0 + 2048 + slot);
      acc[0][0] = __builtin_amdgcn_mfma_f32_32x32x16_bf16(a0, h0, acc[0][0], 0, 0, 0);
      acc[0][1] = __builtin_amdgcn_mfma_f32_32x32x16_bf16(a0, h1, acc[0][1], 0, 0, 0);
      acc[1][0] = __builtin_amdgcn_mfma_f32_32x32x16_bf16(a1, h0, acc[1][0], 0, 0, 0);
      acc[1][1] = __builtin_amdgcn_mfma_f32_32x32x16_bf16(a1, h1, acc[1][1], 0, 0, 0);
      if (TERMS == 2) {
        bf16x8 w0 = *(const bf16x8*)(lb + woff0 + 8192 + slot);
        bf16x8 w1 = *(const bf16x8*)(lb + woff0 + 8192 + 2048 + slot);
        acc[0][0] = __builtin_amdgcn_mfma_f32_32x32x16_bf16(a0, w0, acc[0][0], 0, 0, 0);
        acc[0][1] = __builtin_amdgcn_mfma_f32_32x32x16_bf16(a0, w1, acc[0][1], 0, 0, 0);
        acc[1][0] = __builtin_amdgcn_mfma_f32_32x32x16_bf16(a1, w0, acc[1][0], 0, 0, 0);
        acc[1][1] = __builtin_amdgcn_mfma_f32_32x32x16_bf16(a1, w1, acc[1][1], 0, 0, 0);
      }
    }
    asm volatile("s_waitcnt vmcnt(0)" ::: "memory");
    __syncthreads();
  }

  const int m0 = mt * 128, n0 = nt * 128;
  const float b0 = bias[n0 + wn * 64 + (l & 31)];
  const float b1 = bias[n0 + wn * 64 + 32 + (l & 31)];
#pragma unroll
  for (int rb = 0; rb < 2; rb++) {
    const int rowb = m0 + wm * 64 + rb * 32 + 4 * (l >> 5);
#pragma unroll
    for (int cb = 0; cb < 2; cb++) {
      const int col = n0 + wn * 64 + cb * 32 + (l & 31);
      const float bb = cb ? b1 : b0;
#pragma unroll
      for (int r = 0; r < 16; r++) {
        const int row = rowb + (r & 3) + 8 * (r >> 2);
        C[(size_t)row * 2048 + col] = f2bf(acc[rb][cb][r] + bb);
      }
    }
  }
}

// ============================================================================
// Fused bidirectional recurrence — 1-sync epoch, ballot poll, per-wave arrive.
// 256 blocks: dir = bid>>7, jg = (bid&127)>>1 (8 j-cols), bg = bid&1 (32 b).
// Epoch: [ballot-poll 8 leaves] -> A-frag IF->VGPR (split vmcnt(8)) ->
// 24 MFMA -> p_lds[s&1] -> syncthreads -> update -> h+out stores -> vmcnt(0)
// -> lane0-of-wave arrives (leaf jg>>3, target 32/step) -> xz prefetch.
// Safety: reads(s) precede update(s) precede arrival(s); poll covers the
// whole group, so buffer s&1 is never overwritten while any reader is in s.
// ============================================================================
__global__ __launch_bounds__(256, 1) void lstm_fused(
    const unsigned short* __restrict__ xzF,
    const unsigned short* __restrict__ xzB,
    const float* __restrict__ UtF,
    const float* __restrict__ UtB,
    float* __restrict__ outF32,
    unsigned short* __restrict__ outB16,
    float* __restrict__ hbuf,
    float* __restrict__ stateh, float* __restrict__ statec,
    unsigned* __restrict__ bar) {
  __shared__ float p_lds[2][4][32][36];

  const int tid = threadIdx.x;
  const int bid = blockIdx.x;
  const int dir = bid >> 7;
  const int jg  = (bid & 127) >> 1;
  const int bg  = bid & 1;
  const int grp = dir * 2 + bg;

  const unsigned short* xz = dir ? xzB : xzF;
  const float* Ut = dir ? UtB : UtF;
  char* hbuf_c = (char*)hbuf;

  const int l  = tid & 63;
  const int wv = tid >> 6;

  // ---- U fragments in registers (loop-invariant B operands) ----
  bf16x8 uh8[8], ul8[8];
  {
    const int c = l & 31;
    const size_t gcol = (size_t)((c >> 3) * 512 + jg * 8 + (c & 7));
#pragma unroll
    for (int ks = 0; ks < 8; ks++) {
      const float* src = Ut + gcol * 512 + (wv * 8 + ks) * 16 + ((l >> 5) << 3);
      bf16x8 hh, ll;
#pragma unroll
      for (int e = 0; e < 8; e++) {
        float f = src[e];
        unsigned short us = f2bf(f);
        hh[e] = (short)us;
        ll[e] = (short)f2bf(f - bf2f(us));
      }
      uh8[ks] = hh;
      ul8[ks] = ll;
    }
  }

  const int ub = tid >> 3;
  const int jl = tid & 7;
  const int b  = bg * 32 + ub;
  const int j  = jg * 8 + jl;

  unsigned* leafArr = bar + grp * 128;
  unsigned* arriveLeaf = leafArr + ((jg >> 3) << 4);
  const unsigned* pollLeaf = leafArr + ((l & 7) << 4);

  const unsigned short* xzb = xz + (size_t)b * (512 * 2048) + j;

  float creg = 0.0f;
  float zx0, zx1, zx2, zx3;
  {
    const unsigned short* p = xzb + (size_t)(dir ? 511 : 0) * 2048;
    zx0 = bf2f(p[0]); zx1 = bf2f(p[512]);
    zx2 = bf2f(p[1024]); zx3 = bf2f(p[1536]);
  }

  const int aoff = ((wv * 16 + (l >> 5)) * 32 + (l & 31)) * 16;
  const int poff = jg * 512 + ub * 16 + jl * 2;

  const int colp = dir * 512 + j;
  const int p_kt = colp >> 5, p_g = (colp >> 3) & 3, p_e = colp & 7;

  for (int s = 0; s < 512; s++) {
    const int tt = dir ? (511 - s) : s;

    if (s > 0) {
      // ---- parallel ballot poll: lane l watches leaf (l&7) ----
      {
        const unsigned tgt = 32u * (unsigned)s;
        while (true) {
          unsigned v = __hip_atomic_load(pollLeaf, __ATOMIC_RELAXED,
                                         __HIP_MEMORY_SCOPE_AGENT);
          if (__all((int)(v >= tgt))) break;
          __builtin_amdgcn_s_sleep(1);
        }
      }
      // ---- direct IF->VGPR A-frag loads; hh MFMAs start under hl loads ----
      const char* sb = hbuf_c + (size_t)(grp * 2 + (s & 1)) * 65536;
      bf16x8 ahh[8], ahl[8];
#pragma unroll
      for (int ks = 0; ks < 8; ks++) {
        const char* p = sb + aoff + ks * 1024;
        asm volatile("global_load_dwordx4 %0, %1, off sc0 sc1"
                     : "=v"(ahh[ks]) : "v"(p) : "memory");
      }
#pragma unroll
      for (int ks = 0; ks < 8; ks++) {
        const char* p = sb + aoff + ks * 1024 + 32768;
        asm volatile("global_load_dwordx4 %0, %1, off sc0 sc1"
                     : "=v"(ahl[ks]) : "v"(p) : "memory");
      }
      f32x16 acc;
#pragma unroll
      for (int r = 0; r < 16; r++) acc[r] = 0.0f;
      asm volatile("s_waitcnt vmcnt(8)" ::: "memory");
      __builtin_amdgcn_sched_barrier(0);
#pragma unroll
      for (int ks = 0; ks < 8; ks++)
        acc = __builtin_amdgcn_mfma_f32_32x32x16_bf16(ahh[ks], uh8[ks], acc, 0, 0, 0);
      asm volatile("s_waitcnt vmcnt(0)" ::: "memory");
      __builtin_amdgcn_sched_barrier(0);
#pragma unroll
      for (int ks = 0; ks < 8; ks++) {
        acc = __builtin_amdgcn_mfma_f32_32x32x16_bf16(ahl[ks], uh8[ks], acc, 0, 0, 0);
        acc = __builtin_amdgcn_mfma_f32_32x32x16_bf16(ahh[ks], ul8[ks], acc, 0, 0, 0);
      }
#pragma unroll
      for (int r = 0; r < 16; r++) {
        const int row = (r & 3) + 8 * (r >> 2) + 4 * (l >> 5);
        p_lds[s & 1][wv][row][l & 31] = acc[r];
      }
    }
    __syncthreads();

    // ---- update: thread owns (b, j) ----
    float h;
    {
      float z0 = zx0, z1 = zx1, z2 = zx2, z3 = zx3;
      if (s > 0) {
#pragma unroll
        for (int w = 0; w < 4; w++) {
          z0 += p_lds[s & 1][w][ub][jl];
          z1 += p_lds[s & 1][w][ub][8 + jl];
          z2 += p_lds[s & 1][w][ub][16 + jl];
          z3 += p_lds[s & 1][w][ub][24 + jl];
        }
      }
      float si = fsigmoid(z0);
      float sf = fsigmoid(z1);
      float tg = ftanh(z2);
      float so = fsigmoid(z3);
      creg = fmaf(sf, creg, si * tg);
      h = so * ftanh(creg);
    }

    const int m = b * 512 + tt;
    if (s < 511) {
      unsigned short hhs = f2bf(h);
      unsigned short hls = f2bf(h - bf2f(hhs));
      char* db = hbuf_c + (size_t)(grp * 2 + ((s & 1) ^ 1)) * 65536;
      char* pj = db + poff;
      unsigned vh = hhs, vl = hls;
      asm volatile("global_store_short %0, %1, off sc0 sc1"
                   :: "v"(pj), "v"(vh) : "memory");
      asm volatile("global_store_short %0, %1, off sc0 sc1"
                   :: "v"(pj + 32768), "v"(vl) : "memory");
      if (outB16) {
        const int rm = m & 127, mt = m >> 7;
        outB16[(((size_t)(mt * 32 + p_kt) * 128 + rm) << 5) +
               (p_g ^ (rm & 3)) * 8 + p_e] = f2bf(h);
      } else {
        outF32[((size_t)m) * 1024 + colp] = h;
      }
      asm volatile("s_waitcnt vmcnt(0)" ::: "memory");
      // per-wave arrival: this wave's stores are drained
      if ((tid & 63) == 0)
        __hip_atomic_fetch_add(arriveLeaf, 1u, __ATOMIC_RELAXED,
                               __HIP_MEMORY_SCOPE_AGENT);
      // ---- poll shadow: next-xz prefetch ----
      {
        const int tn = dir ? (510 - s) : (s + 1);
        const unsigned short* p = xzb + (size_t)tn * 2048;
        zx0 = bf2f(p[0]); zx1 = bf2f(p[512]);
        zx2 = bf2f(p[1024]); zx3 = bf2f(p[1536]);
      }
    } else {
      if (outB16) {
        const int rm = m & 127, mt = m >> 7;
        outB16[(((size_t)(mt * 32 + p_kt) * 128 + rm) << 5) +
               (p_g ^ (rm & 3)) * 8 + p_e] = f2bf(h);
      } else {
        outF32[((size_t)m) * 1024 + colp] = h;
      }
      if (stateh != nullptr) {
        stateh[b * 1024 + colp] = h;
        statec[b * 1024 + colp] = creg;
      }
    }
  }
}

// ---------------------------------------------------------------------------
extern "C" void kernel_launch(void* const* d_in, const int* in_sizes, int n_in,
                              void* d_out, int out_size, void* d_ws, size_t ws_size,
                              hipStream_t stream) {
  const int*   ids = (const int*)d_in[0];
  const float* emb = (const float*)d_in[1];
  const float* W1f = (const float*)d_in[2];
  const float* U1f = (const float*)d_in[3];
  const float* b1f = (const float*)d_in[4];
  const float* W1b = (const float*)d_in[5];
  const float* U1b = (const float*)d_in[6];
  const float* b1b = (const float*)d_in[7];
  const float* W2f = (const float*)d_in[8];
  const float* U2f = (const float*)d_in[9];
  const float* b2f = (const float*)d_in[10];
  const float* W2b = (const float*)d_in[11];
  const float* U2b = (const float*)d_in[12];
  const float* b2b = (const float*)d_in[13];
  float* out = (float*)d_out;

  char* ws = (char*)d_ws;
  unsigned short* xzF = (unsigned short*)(ws + 0ull);
  unsigned short* xzB = (unsigned short*)(ws + 134217728ull);
  float* Ut1f = (float*)(ws + 268435456ull);
  float* Ut1b = Ut1f + 1048576;
  float* Ut2f = Ut1b + 1048576;
  float* Ut2b = Ut2f + 1048576;
  float* hbuf = (float*)(ws + 285212672ull);
  unsigned* bar = (unsigned*)(ws + 285736960ull);

  char* outc = (char*)d_out;
  unsigned short* l1pan = (unsigned short*)outc;
  unsigned short* A1pan = (unsigned short*)(outc + 67108864ull);
  unsigned short* Wh1f = (unsigned short*)(outc + 100663296ull);
  unsigned short* Wl1f = (unsigned short*)(outc + 102760448ull);
  unsigned short* Wh1b = (unsigned short*)(outc + 104857600ull);
  unsigned short* Wl1b = (unsigned short*)(outc + 106954752ull);
  unsigned short* Wh2f = (unsigned short*)(outc + 109051904ull);
  unsigned short* Wl2f = (unsigned short*)(outc + 113246208ull);
  unsigned short* Wh2b = (unsigned short*)(outc + 117440512ull);
  unsigned short* Wl2b = (unsigned short*)(outc + 121634816ull);

  transpose_u<<<1024, 256, 0, stream>>>(U1f, Ut1f);
  transpose_u<<<1024, 256, 0, stream>>>(U1b, Ut1b);
  transpose_u<<<1024, 256, 0, stream>>>(U2f, Ut2f);
  transpose_u<<<1024, 256, 0, stream>>>(U2b, Ut2b);
  build_w_panels<<<1024, 256, 0, stream>>>(W1f, Wh1f, Wl1f, 16);
  build_w_panels<<<1024, 256, 0, stream>>>(W1b, Wh1b, Wl1b, 16);
  build_w_panels<<<2048, 256, 0, stream>>>(W2f, Wh2f, Wl2f, 32);
  build_w_panels<<<2048, 256, 0, stream>>>(W2b, Wh2b, Wl2b, 32);
  build_a1_panels<<<8192, 256, 0, stream>>>(ids, emb, A1pan);

  // layer-1 projections (merged F+B, 1-term)
  gemm_panel<16, 1><<<8192, 256, 0, stream>>>(A1pan, Wh1f, Wl1f, Wh1b, Wl1b,
                                              b1f, b1b, xzF, xzB);
  hipMemsetAsync(bar, 0, 4096, stream);
  lstm_fused<<<NBLK_LSTM, 256, 0, stream>>>(xzF, xzB, Ut1f, Ut1b,
                                            nullptr, l1pan, hbuf,
                                            nullptr, nullptr, bar);
  // layer-2 projections (merged F+B, 2-term)
  gemm_panel<32, 2><<<8192, 256, 0, stream>>>(l1pan, Wh2f, Wl2f, Wh2b, Wl2b,
                                              b2f, b2b, xzF, xzB);
  hipMemsetAsync(bar, 0, 4096, stream);
  lstm_fused<<<NBLK_LSTM, 256, 0, stream>>>(xzF, xzB, Ut2f, Ut2b,
                                            out, nullptr, hbuf,
                                            out + 33554432, out + 33619968, bar);
}

// Round 14
// 4015.981 us; speedup vs baseline: 1.2442x; 1.0150x over previous
//
#include <hip/hip_runtime.h>
#include <math.h>

// ---------------------------------------------------------------------------
// Encoder: 2-layer bidirectional LSTM, B=64, T=512, E=H=512, fp32 in/out.
// Round 14: lstm pre-arrival drain covers ONLY the 2 IF h-stores (out-store
// moved to poll shadow, drained by next epoch's in-order vmcnt(8)).
// Setup merged: 1 transpose dispatch, 2 W-panel dispatches, bar zeroed by
// gemm block 0 (memsets deleted).
// ---------------------------------------------------------------------------

#define NBLK_LSTM 256

typedef __attribute__((ext_vector_type(8))) short bf16x8;
typedef __attribute__((ext_vector_type(16))) float f32x16;

__device__ __forceinline__ float bf2f(unsigned short u) {
  return __uint_as_float(((unsigned)u) << 16);
}
__device__ __forceinline__ unsigned short f2bf(float f) {
  unsigned u = __float_as_uint(f);
  unsigned r = (u + 0x7FFFu + ((u >> 16) & 1u)) >> 16;
  return (unsigned short)r;
}
__device__ __forceinline__ float fsigmoid(float x) {
  return 1.0f / (1.0f + __expf(-x));
}
__device__ __forceinline__ float ftanh(float x) {
  return 1.0f - 2.0f / (1.0f + __expf(2.0f * x));
}
__device__ __forceinline__ void gload16(const void* g, void* l) {
  __builtin_amdgcn_global_load_lds(
      (const __attribute__((address_space(1))) unsigned int*)g,
      (__attribute__((address_space(3))) unsigned int*)l, 16, 0, 0);
}

// ------------- merged U transpose: 4 matrices in one dispatch ---------------
__global__ __launch_bounds__(256) void transpose_u4(
    const float* __restrict__ U0, const float* __restrict__ U1,
    const float* __restrict__ U2, const float* __restrict__ U3,
    float* __restrict__ T0, float* __restrict__ T1,
    float* __restrict__ T2, float* __restrict__ T3) {
  __shared__ float tile[32][33];
  const int which = blockIdx.x >> 10;
  const int inner = blockIdx.x & 1023;
  const float* U = which == 0 ? U0 : which == 1 ? U1 : which == 2 ? U2 : U3;
  float* Ut      = which == 0 ? T0 : which == 1 ? T1 : which == 2 ? T2 : T3;
  int kt = inner & 15;
  int ct = inner >> 4;
  int k0 = kt * 32, c0 = ct * 32;
  int tx = threadIdx.x & 31, ty = threadIdx.x >> 5;
#pragma unroll
  for (int i = 0; i < 32; i += 8)
    tile[ty + i][tx] = U[(size_t)(k0 + ty + i) * 2048 + c0 + tx];
  __syncthreads();
#pragma unroll
  for (int i = 0; i < 32; i += 8)
    Ut[(size_t)(c0 + ty + i) * 512 + k0 + tx] = tile[tx][ty + i];
}

// ------ W -> split bf16 panels [16 nt][KT][128][32], merged F+B halves ------
template <int KT>
__global__ __launch_bounds__(256) void build_w_panels(
    const float* __restrict__ WF, unsigned short* __restrict__ WhFp,
    unsigned short* __restrict__ WlFp,
    const float* __restrict__ WB, unsigned short* __restrict__ WhBp,
    unsigned short* __restrict__ WlBp) {
  __shared__ float tile[32][33];
  const int tid = threadIdx.x;
  const int nInner = KT * 64;
  const int half = blockIdx.x / nInner;
  const int inner = blockIdx.x % nInner;
  const float* W = half ? WB : WF;
  unsigned short* Wh = half ? WhBp : WhFp;
  unsigned short* Wl = half ? WlBp : WlFp;
  int kt = inner % KT;
  int ct = inner / KT;
  int k0 = kt * 32, c0 = ct * 32;
  int tx = tid & 31, ty = tid >> 5;
#pragma unroll
  for (int i = 0; i < 32; i += 8)
    tile[ty + i][tx] = W[(size_t)(k0 + ty + i) * 2048 + c0 + tx];
  __syncthreads();
  const int t = tid & 127;
  const int cl = t & 31, g = t >> 5;
  const int c = c0 + cl;
  const int rm = c & 127, nt = c >> 7;
  const int slot = g ^ (rm & 3);
  size_t off = (((size_t)(nt * KT + kt) * 128 + rm) << 5) + slot * 8;
  bf16x8 hh, ll;
#pragma unroll
  for (int e = 0; e < 8; e++) {
    float f = tile[g * 8 + e][cl];
    unsigned short h = f2bf(f);
    hh[e] = (short)h;
    ll[e] = (short)f2bf(f - bf2f(h));
  }
  if (tid < 128) *(bf16x8*)(Wh + off) = hh;
  else           *(bf16x8*)(Wl + off) = ll;
}

// ------- A1 panels: bf16(emb[ids[m]]) -> [256 mt][16 kt][128][32] ----------
__global__ __launch_bounds__(256) void build_a1_panels(
    const int* __restrict__ ids, const float* __restrict__ emb,
    unsigned short* __restrict__ Apan) {
  const int tid = threadIdx.x;
  const int l = tid & 63, wv = tid >> 6;
  const int m = blockIdx.x * 4 + wv;
  const float* src = emb + (size_t)ids[m] * 512 + l * 8;
  float4 v0 = *(const float4*)src;
  float4 v1 = *(const float4*)(src + 4);
  float f[8] = {v0.x, v0.y, v0.z, v0.w, v1.x, v1.y, v1.z, v1.w};
  bf16x8 hh;
#pragma unroll
  for (int e = 0; e < 8; e++) hh[e] = (short)f2bf(f[e]);
  const int rm = m & 127, mt = m >> 7;
  const int kt = l >> 2, g = l & 3;
  const int slot = g ^ (rm & 3);
  *(bf16x8*)(Apan + (((size_t)(mt * 16 + kt) * 128 + rm) << 5) + slot * 8) = hh;
}

// ============================================================================
// Panel GEMM, merged F/B dispatch; block 0 zeroes the lstm barrier region.
// TERMS=2: C = A @ (Wh + Wl) + b.  TERMS=1: C = A @ Wh + b.
// ============================================================================
template <int KT, int TERMS>
__global__ __launch_bounds__(256) void gemm_panel(
    const unsigned short* __restrict__ Apan,
    const unsigned short* __restrict__ WhF,
    const unsigned short* __restrict__ WlF,
    const unsigned short* __restrict__ WhB,
    const unsigned short* __restrict__ WlB,
    const float* __restrict__ bF, const float* __restrict__ bB,
    unsigned short* __restrict__ CF, unsigned short* __restrict__ CB,
    unsigned* __restrict__ barz) {
  __shared__ __align__(16) char lds[2][24576];

  const int tid = threadIdx.x;
  if (blockIdx.x == 0 && tid < 128) {
    uint4 z = {0u, 0u, 0u, 0u};
    ((uint4*)barz)[tid] = z;   // 2 KB: 4 groups x 128 unsigneds
  }
  const int half = blockIdx.x >> 12;
  const int inner = blockIdx.x & 4095;
  const int mt = inner & 255;
  const int nt = inner >> 8;
  const int l = tid & 63;
  const int wv = tid >> 6;
  const int wm = wv >> 1, wn = wv & 1;

  const unsigned short* WhP = half ? WhB : WhF;
  const unsigned short* WlP = half ? WlB : WlF;
  const float* bias = half ? bB : bF;
  unsigned short* C = half ? CB : CF;

  const char* aSrc = (const char*)(Apan + (size_t)mt * KT * 4096);
  const char* hSrc = (const char*)(WhP + (size_t)nt * KT * 4096);
  const char* lSrc = (const char*)(WlP + (size_t)nt * KT * 4096);
  const int wvo = wv * 1024;
  const int lo16 = l * 16;

  f32x16 acc[2][2];
#pragma unroll
  for (int rb = 0; rb < 2; rb++)
#pragma unroll
    for (int cb = 0; cb < 2; cb++)
#pragma unroll
      for (int r = 0; r < 16; r++) acc[rb][cb][r] = 0.0f;

  auto STAGE = [&](int buf, int t) {
    const char* ga = aSrc + (size_t)t * 8192 + wvo + lo16;
    const char* gh = hSrc + (size_t)t * 8192 + wvo + lo16;
    char* da = &lds[buf][0] + wvo;
    char* dh = &lds[buf][8192] + wvo;
    gload16(ga, da);
    gload16(ga + 4096, da + 4096);
    gload16(gh, dh);
    gload16(gh + 4096, dh + 4096);
    if (TERMS == 2) {
      const char* gl = lSrc + (size_t)t * 8192 + wvo + lo16;
      char* dl = &lds[buf][16384] + wvo;
      gload16(gl, dl);
      gload16(gl + 4096, dl + 4096);
    }
  };

  STAGE(0, 0);
  asm volatile("s_waitcnt vmcnt(0)" ::: "memory");
  __syncthreads();

  const int aoff0 = (wm * 64 + (l & 31)) * 64;
  const int woff0 = 8192 + (wn * 64 + (l & 31)) * 64;
  const int gbase = l >> 5;
  const int gx = l & 3;

  for (int t = 0; t < KT; t++) {
    if (t + 1 < KT) STAGE((t + 1) & 1, t + 1);
    const char* lb = lds[t & 1];
#pragma unroll
    for (int ks = 0; ks < 2; ks++) {
      const int slot = (((ks << 1) + gbase) ^ gx) << 4;
      bf16x8 a0 = *(const bf16x8*)(lb + aoff0 + slot);
      bf16x8 a1 = *(const bf16x8*)(lb + aoff0 + 2048 + slot);
      bf16x8 h0 = *(const bf16x8*)(lb + woff0 + slot);
      bf16x8 h1 = *(const bf16x8*)(lb + woff0 + 2048 + slot);
      acc[0][0] = __builtin_amdgcn_mfma_f32_32x32x16_bf16(a0, h0, acc[0][0], 0, 0, 0);
      acc[0][1] = __builtin_amdgcn_mfma_f32_32x32x16_bf16(a0, h1, acc[0][1], 0, 0, 0);
      acc[1][0] = __builtin_amdgcn_mfma_f32_32x32x16_bf16(a1, h0, acc[1][0], 0, 0, 0);
      acc[1][1] = __builtin_amdgcn_mfma_f32_32x32x16_bf16(a1, h1, acc[1][1], 0, 0, 0);
      if (TERMS == 2) {
        bf16x8 w0 = *(const bf16x8*)(lb + woff0 + 8192 + slot);
        bf16x8 w1 = *(const bf16x8*)(lb + woff0 + 8192 + 2048 + slot);
        acc[0][0] = __builtin_amdgcn_mfma_f32_32x32x16_bf16(a0, w0, acc[0][0], 0, 0, 0);
        acc[0][1] = __builtin_amdgcn_mfma_f32_32x32x16_bf16(a0, w1, acc[0][1], 0, 0, 0);
        acc[1][0] = __builtin_amdgcn_mfma_f32_32x32x16_bf16(a1, w0, acc[1][0], 0, 0, 0);
        acc[1][1] = __builtin_amdgcn_mfma_f32_32x32x16_bf16(a1, w1, acc[1][1], 0, 0, 0);
      }
    }
    asm volatile("s_waitcnt vmcnt(0)" ::: "memory");
    __syncthreads();
  }

  const int m0 = mt * 128, n0 = nt * 128;
  const float b0 = bias[n0 + wn * 64 + (l & 31)];
  const float b1 = bias[n0 + wn * 64 + 32 + (l & 31)];
#pragma unroll
  for (int rb = 0; rb < 2; rb++) {
    const int rowb = m0 + wm * 64 + rb * 32 + 4 * (l >> 5);
#pragma unroll
    for (int cb = 0; cb < 2; cb++) {
      const int col = n0 + wn * 64 + cb * 32 + (l & 31);
      const float bb = cb ? b1 : b0;
#pragma unroll
      for (int r = 0; r < 16; r++) {
        const int row = rowb + (r & 3) + 8 * (r >> 2);
        C[(size_t)row * 2048 + col] = f2bf(acc[rb][cb][r] + bb);
      }
    }
  }
}

// ============================================================================
// Fused bidirectional recurrence — minimal-drain edition.
// Epoch: [ballot poll] -> 16 A-loads -> vmcnt(8) (in-order: prev out-store +
// xz prefetch + hh all complete) -> 8 hh MFMA -> vmcnt(0) -> 16 MFMA ->
// p_lds[s&1] -> sync -> update -> 2 IF h-stores -> vmcnt(0) (IF only) ->
// per-wave arrive -> [shadow: out-store + xz prefetch].
// ============================================================================
__global__ __launch_bounds__(256, 1) void lstm_fused(
    const unsigned short* __restrict__ xzF,
    const unsigned short* __restrict__ xzB,
    const float* __restrict__ UtF,
    const float* __restrict__ UtB,
    float* __restrict__ outF32,
    unsigned short* __restrict__ outB16,
    float* __restrict__ hbuf,
    float* __restrict__ stateh, float* __restrict__ statec,
    unsigned* __restrict__ bar) {
  __shared__ float p_lds[2][4][32][36];

  const int tid = threadIdx.x;
  const int bid = blockIdx.x;
  const int dir = bid >> 7;
  const int jg  = (bid & 127) >> 1;
  const int bg  = bid & 1;
  const int grp = dir * 2 + bg;

  const unsigned short* xz = dir ? xzB : xzF;
  const float* Ut = dir ? UtB : UtF;
  char* hbuf_c = (char*)hbuf;

  const int l  = tid & 63;
  const int wv = tid >> 6;

  // ---- U fragments in registers (loop-invariant B operands) ----
  bf16x8 uh8[8], ul8[8];
  {
    const int c = l & 31;
    const size_t gcol = (size_t)((c >> 3) * 512 + jg * 8 + (c & 7));
#pragma unroll
    for (int ks = 0; ks < 8; ks++) {
      const float* src = Ut + gcol * 512 + (wv * 8 + ks) * 16 + ((l >> 5) << 3);
      bf16x8 hh, ll;
#pragma unroll
      for (int e = 0; e < 8; e++) {
        float f = src[e];
        unsigned short us = f2bf(f);
        hh[e] = (short)us;
        ll[e] = (short)f2bf(f - bf2f(us));
      }
      uh8[ks] = hh;
      ul8[ks] = ll;
    }
  }

  const int ub = tid >> 3;
  const int jl = tid & 7;
  const int b  = bg * 32 + ub;
  const int j  = jg * 8 + jl;

  unsigned* leafArr = bar + grp * 128;
  unsigned* arriveLeaf = leafArr + ((jg >> 3) << 4);
  const unsigned* pollLeaf = leafArr + ((l & 7) << 4);

  const unsigned short* xzb = xz + (size_t)b * (512 * 2048) + j;

  float creg = 0.0f;
  float zx0, zx1, zx2, zx3;
  {
    const unsigned short* p = xzb + (size_t)(dir ? 511 : 0) * 2048;
    zx0 = bf2f(p[0]); zx1 = bf2f(p[512]);
    zx2 = bf2f(p[1024]); zx3 = bf2f(p[1536]);
  }

  const int aoff = ((wv * 16 + (l >> 5)) * 32 + (l & 31)) * 16;
  const int poff = jg * 512 + ub * 16 + jl * 2;

  const int colp = dir * 512 + j;
  const int p_kt = colp >> 5, p_g = (colp >> 3) & 3, p_e = colp & 7;

  for (int s = 0; s < 512; s++) {
    const int tt = dir ? (511 - s) : s;

    if (s > 0) {
      // ---- parallel ballot poll: lane l watches leaf (l&7) ----
      {
        const unsigned tgt = 32u * (unsigned)s;
        while (true) {
          unsigned v = __hip_atomic_load(pollLeaf, __ATOMIC_RELAXED,
                                         __HIP_MEMORY_SCOPE_AGENT);
          if (__all((int)(v >= tgt))) break;
          __builtin_amdgcn_s_sleep(1);
        }
      }
      // ---- direct IF->VGPR A-frag loads; hh MFMAs start under hl loads ----
      const char* sb = hbuf_c + (size_t)(grp * 2 + (s & 1)) * 65536;
      bf16x8 ahh[8], ahl[8];
#pragma unroll
      for (int ks = 0; ks < 8; ks++) {
        const char* p = sb + aoff + ks * 1024;
        asm volatile("global_load_dwordx4 %0, %1, off sc0 sc1"
                     : "=v"(ahh[ks]) : "v"(p) : "memory");
      }
#pragma unroll
      for (int ks = 0; ks < 8; ks++) {
        const char* p = sb + aoff + ks * 1024 + 32768;
        asm volatile("global_load_dwordx4 %0, %1, off sc0 sc1"
                     : "=v"(ahl[ks]) : "v"(p) : "memory");
      }
      f32x16 acc;
#pragma unroll
      for (int r = 0; r < 16; r++) acc[r] = 0.0f;
      asm volatile("s_waitcnt vmcnt(8)" ::: "memory");
      __builtin_amdgcn_sched_barrier(0);
#pragma unroll
      for (int ks = 0; ks < 8; ks++)
        acc = __builtin_amdgcn_mfma_f32_32x32x16_bf16(ahh[ks], uh8[ks], acc, 0, 0, 0);
      asm volatile("s_waitcnt vmcnt(0)" ::: "memory");
      __builtin_amdgcn_sched_barrier(0);
#pragma unroll
      for (int ks = 0; ks < 8; ks++) {
        acc = __builtin_amdgcn_mfma_f32_32x32x16_bf16(ahl[ks], uh8[ks], acc, 0, 0, 0);
        acc = __builtin_amdgcn_mfma_f32_32x32x16_bf16(ahh[ks], ul8[ks], acc, 0, 0, 0);
      }
#pragma unroll
      for (int r = 0; r < 16; r++) {
        const int row = (r & 3) + 8 * (r >> 2) + 4 * (l >> 5);
        p_lds[s & 1][wv][row][l & 31] = acc[r];
      }
    }
    __syncthreads();

    // ---- update: thread owns (b, j) ----
    float h;
    {
      float z0 = zx0, z1 = zx1, z2 = zx2, z3 = zx3;
      if (s > 0) {
#pragma unroll
        for (int w = 0; w < 4; w++) {
          z0 += p_lds[s & 1][w][ub][jl];
          z1 += p_lds[s & 1][w][ub][8 + jl];
          z2 += p_lds[s & 1][w][ub][16 + jl];
          z3 += p_lds[s & 1][w][ub][24 + jl];
        }
      }
      float si = fsigmoid(z0);
      float sf = fsigmoid(z1);
      float tg = ftanh(z2);
      float so = fsigmoid(z3);
      creg = fmaf(sf, creg, si * tg);
      h = so * ftanh(creg);
    }

    const int m = b * 512 + tt;
    if (s < 511) {
      // ---- 2 IF h-stores; drain ONLY these before arrival ----
      unsigned short hhs = f2bf(h);
      unsigned short hls = f2bf(h - bf2f(hhs));
      char* db = hbuf_c + (size_t)(grp * 2 + ((s & 1) ^ 1)) * 65536;
      char* pj = db + poff;
      unsigned vh = hhs, vl = hls;
      asm volatile("global_store_short %0, %1, off sc0 sc1"
                   :: "v"(pj), "v"(vh) : "memory");
      asm volatile("global_store_short %0, %1, off sc0 sc1"
                   :: "v"(pj + 32768), "v"(vl) : "memory");
      asm volatile("s_waitcnt vmcnt(0)" ::: "memory");
      if ((tid & 63) == 0)
        __hip_atomic_fetch_add(arriveLeaf, 1u, __ATOMIC_RELAXED,
                               __HIP_MEMORY_SCOPE_AGENT);
      // ---- poll shadow: out-store (plain) + next-xz prefetch ----
      if (outB16) {
        const int rm = m & 127, mt = m >> 7;
        outB16[(((size_t)(mt * 32 + p_kt) * 128 + rm) << 5) +
               (p_g ^ (rm & 3)) * 8 + p_e] = f2bf(h);
      } else {
        outF32[((size_t)m) * 1024 + colp] = h;
      }
      {
        const int tn = dir ? (510 - s) : (s + 1);
        const unsigned short* p = xzb + (size_t)tn * 2048;
        zx0 = bf2f(p[0]); zx1 = bf2f(p[512]);
        zx2 = bf2f(p[1024]); zx3 = bf2f(p[1536]);
      }
    } else {
      if (outB16) {
        const int rm = m & 127, mt = m >> 7;
        outB16[(((size_t)(mt * 32 + p_kt) * 128 + rm) << 5) +
               (p_g ^ (rm & 3)) * 8 + p_e] = f2bf(h);
      } else {
        outF32[((size_t)m) * 1024 + colp] = h;
      }
      if (stateh != nullptr) {
        stateh[b * 1024 + colp] = h;
        statec[b * 1024 + colp] = creg;
      }
    }
  }
}

// ---------------------------------------------------------------------------
extern "C" void kernel_launch(void* const* d_in, const int* in_sizes, int n_in,
                              void* d_out, int out_size, void* d_ws, size_t ws_size,
                              hipStream_t stream) {
  const int*   ids = (const int*)d_in[0];
  const float* emb = (const float*)d_in[1];
  const float* W1f = (const float*)d_in[2];
  const float* U1f = (const float*)d_in[3];
  const float* b1f = (const float*)d_in[4];
  const float* W1b = (const float*)d_in[5];
  const float* U1b = (const float*)d_in[6];
  const float* b1b = (const float*)d_in[7];
  const float* W2f = (const float*)d_in[8];
  const float* U2f = (const float*)d_in[9];
  const float* b2f = (const float*)d_in[10];
  const float* W2b = (const float*)d_in[11];
  const float* U2b = (const float*)d_in[12];
  const float* b2b = (const float*)d_in[13];
  float* out = (float*)d_out;

  char* ws = (char*)d_ws;
  unsigned short* xzF = (unsigned short*)(ws + 0ull);
  unsigned short* xzB = (unsigned short*)(ws + 134217728ull);
  float* Ut1f = (float*)(ws + 268435456ull);
  float* Ut1b = Ut1f + 1048576;
  float* Ut2f = Ut1b + 1048576;
  float* Ut2b = Ut2f + 1048576;
  float* hbuf = (float*)(ws + 285212672ull);
  unsigned* bar = (unsigned*)(ws + 285736960ull);

  char* outc = (char*)d_out;
  unsigned short* l1pan = (unsigned short*)outc;
  unsigned short* A1pan = (unsigned short*)(outc + 67108864ull);
  unsigned short* Wh1f = (unsigned short*)(outc + 100663296ull);
  unsigned short* Wl1f = (unsigned short*)(outc + 102760448ull);
  unsigned short* Wh1b = (unsigned short*)(outc + 104857600ull);
  unsigned short* Wl1b = (unsigned short*)(outc + 106954752ull);
  unsigned short* Wh2f = (unsigned short*)(outc + 109051904ull);
  unsigned short* Wl2f = (unsigned short*)(outc + 113246208ull);
  unsigned short* Wh2b = (unsigned short*)(outc + 117440512ull);
  unsigned short* Wl2b = (unsigned short*)(outc + 121634816ull);

  transpose_u4<<<4096, 256, 0, stream>>>(U1f, U1b, U2f, U2b,
                                         Ut1f, Ut1b, Ut2f, Ut2b);
  build_w_panels<16><<<2048, 256, 0, stream>>>(W1f, Wh1f, Wl1f, W1b, Wh1b, Wl1b);
  build_w_panels<32><<<4096, 256, 0, stream>>>(W2f, Wh2f, Wl2f, W2b, Wh2b, Wl2b);
  build_a1_panels<<<8192, 256, 0, stream>>>(ids, emb, A1pan);

  // layer-1 projections (merged F+B, 1-term; block 0 zeroes bar)
  gemm_panel<16, 1><<<8192, 256, 0, stream>>>(A1pan, Wh1f, Wl1f, Wh1b, Wl1b,
                                              b1f, b1b, xzF, xzB, bar);
  lstm_fused<<<NBLK_LSTM, 256, 0, stream>>>(xzF, xzB, Ut1f, Ut1b,
                                            nullptr, l1pan, hbuf,
                                            nullptr, nullptr, bar);
  // layer-2 projections (merged F+B, 2-term; block 0 re-zeroes bar)
  gemm_panel<32, 2><<<8192, 256, 0, stream>>>(l1pan, Wh2f, Wl2f, Wh2b, Wl2b,
                                              b2f, b2b, xzF, xzB, bar);
  lstm_fused<<<NBLK_LSTM, 256, 0, stream>>>(xzF, xzB, Ut2f, Ut2b,
                                            out, nullptr, hbuf,
                                            out + 33554432, out + 33619968, bar);
}